// Round 8
// baseline (122.663 us; speedup 1.0000x reference)
//
#include <hip/hip_runtime.h>
#include <hip/hip_bf16.h>

typedef __attribute__((ext_vector_type(8))) short short8;
typedef __attribute__((ext_vector_type(4))) float float4v;
typedef __attribute__((ext_vector_type(16))) float float16v;

// Workspace layout (bytes):
//   xT   bf16 [16][34][34][256]                          : 9,469,952
//   Wg   bf16 [9][4][2][8][128][8] (s,pair,nt,g,n,c8)    : 1,179,648
//   biasout f32 [256]                                    : 1,024
#define XT_ELEMS (16*34*34*256)
#define WG_ELEMS (9*4*2*8*128*8)
#define XT_BYTES (XT_ELEMS*2)
#define WG_BYTES (WG_ELEMS*2)

// ---------------------------------------------------------------------------
// Kernel 0: x f32 [16][256][32][32] -> xT bf16 [16][34][34][256].
// 512 blocks = (b, h). float4 reads, LDS transpose, bf16x2 writes.
// Blocks with h<2 also zero the pad ring. ~77 MB HBM => ~12 us floor.
// ---------------------------------------------------------------------------
__global__ __launch_bounds__(256) void k_transpose(const float* __restrict__ x,
                                                   __hip_bfloat16* __restrict__ xT) {
  __shared__ float tile[256 * 33];
  int blk = blockIdx.x;            // b*32 + h
  int h = blk & 31, b = blk >> 5;
  int tid = threadIdx.x;
  {
    int w4 = (tid & 7) * 4, c0 = tid >> 3;
#pragma unroll
    for (int j = 0; j < 8; ++j) {
      int ci = c0 + 32 * j;
      float4 v = *(const float4*)&x[((b * 256 + ci) * 32 + h) * 32 + w4];
      *(float4*)&tile[ci * 33 + w4] = v;
    }
  }
  __syncthreads();
  {
    int c2 = (tid & 127) * 2, wbase = (tid >> 7) * 16;
#pragma unroll
    for (int i = 0; i < 16; ++i) {
      int w = wbase + i;
      __hip_bfloat162 pk;
      pk.x = __float2bfloat16(tile[c2 * 33 + w]);
      pk.y = __float2bfloat16(tile[(c2 + 1) * 33 + w]);
      *(__hip_bfloat162*)&xT[((b * 34 + h + 1) * 34 + (w + 1)) * 256 + c2] = pk;
    }
  }
  if (h < 2) {
    uint4 z4 = {0u, 0u, 0u, 0u};
    int edge = h * 33;
    uint4* rowp = (uint4*)&xT[((b * 34 + edge) * 34) * 256];
    for (int i = tid; i < 1088; i += 256) rowp[i] = z4;
    for (int i = tid; i < 1024; i += 256) {
      int hh = 1 + (i >> 5);
      int c16 = (i & 31) * 8;
      *(uint4*)&xT[((b * 34 + hh) * 34 + edge) * 256 + c16] = z4;
    }
  }
}

// ---------------------------------------------------------------------------
// Kernel 1: build dense M_s = B2_s * B1_s, exact f32 in LDS. 145 blocks.
// ---------------------------------------------------------------------------
__global__ __launch_bounds__(256) void k_build_w(const float* __restrict__ tw1,
                                                 const float* __restrict__ tw2,
                                                 const float* __restrict__ bias,
                                                 __hip_bfloat16* __restrict__ Wg,
                                                 float* __restrict__ biasout) {
  __shared__ float mat[256 * 17];
  __shared__ __align__(16) float tws[2 * 255 * 4];
  int blk = blockIdx.x;
  int tid = threadIdx.x;
  if (blk == 144) {
    if (tid < 256) {
      float a = 0.f;
#pragma unroll
      for (int s = 0; s < 9; ++s) a += bias[s * 256 + tid];
      biasout[tid] = a * (1.f / 9.f);
    }
    return;
  }
  int sidx = blk >> 4;
  int colbase = (blk & 15) * 16;

  for (int i = tid; i < 255 * 4; i += 256) {
    tws[i]           = tw1[sidx * 255 * 4 + i];
    tws[255 * 4 + i] = tw2[sidx * 255 * 4 + i];
  }
  {
    int r = tid;
#pragma unroll
    for (int c = 0; c < 16; ++c) mat[r * 17 + c] = (r == colbase + c) ? 1.f : 0.f;
  }

  int c  = tid & 15;
  int pg = tid >> 4;
  for (int ph = 0; ph < 2; ++ph) {
    for (int si = 0; si < 8; ++si) {
      int lg = ph ? si : (7 - si);
      int st = 1 << lg;
      __syncthreads();
      float x0[8], x1[8], t0[8], t1[8], t2[8], t3[8];
#pragma unroll
      for (int i = 0; i < 8; ++i) {
        int qp = pg * 8 + i;
        int li = qp & (st - 1);
        int gi = qp >> lg;
        int p0 = (gi << (lg + 1)) | li;
        int p1 = p0 + st;
        float4 tv = *(const float4*)&tws[(ph * 255 + st - 1 + li) * 4];
        t0[i] = tv.x; t1[i] = tv.y; t2[i] = tv.z; t3[i] = tv.w;
        x0[i] = mat[p0 * 17 + c];
        x1[i] = mat[p1 * 17 + c];
      }
#pragma unroll
      for (int i = 0; i < 8; ++i) {
        int qp = pg * 8 + i;
        int li = qp & (st - 1);
        int gi = qp >> lg;
        int p0 = (gi << (lg + 1)) | li;
        int p1 = p0 + st;
        mat[p0 * 17 + c] = t0[i] * x0[i] + t1[i] * x1[i];
        mat[p1 * 17 + c] = t2[i] * x0[i] + t3[i] * x1[i];
      }
    }
  }
  __syncthreads();

  // Scatter in GEMM A-staging order: [s][pair][nt][g][nl][c8], fold 1/9.
  for (int idx = tid; idx < 256 * 16; idx += 256) {
    int r = idx >> 4, cc = idx & 15;
    int cg = colbase + cc;
    int pr = cg >> 6, qq = (cg >> 3) & 7, c8 = cg & 7;
    int nt = r >> 7, nl = r & 127;
    int o = ((((sidx * 4 + pr) * 2 + nt) * 8 + qq) * 128 + nl) * 8 + c8;
    Wg[o] = __float2bfloat16(mat[r * 17 + cc] * (1.f / 9.f));
  }
}

// ---------------------------------------------------------------------------
// Kernel 2 (R7: mfma 32x32x16): implicit-GEMM conv, K=64/step, 36 steps.
// Grid 512 = 16 b x 16 ptile(2 rows = 64 pix) x 2 nt; 256 threads (4 waves =
// 2 wm n-half x 2 wk k-half). Wave tile 64n x 64pix = 2x2 of 32x32 MFMA tiles
// -> 32 FLOP per LDS byte (1.5x the 16x16 shape). launch_bounds(256,2) ->
// 2 blocks/CU co-resident (LDS 49 KB).
// A LDS: [g 8][n 128][8ch] per step (16 KB, dbuf). B: [g 8][pos 136][8ch]
// halo (4 rows x 34 w), single-buffered per channel-pair.
// A frag: A[m=lane&31][k=8*(lane>>5)+j]; C/D: col=lane&31,
// row=(reg&3)+8*(reg>>2)+4*(lane>>5)  (m74/m101-verified).
// ---------------------------------------------------------------------------
#define ABUF 16384
#define BBASE (2 * ABUF)
#define LDS_B_SZ (8 * 136 * 16)

__global__ __launch_bounds__(256, 2) void k_gemm(const __hip_bfloat16* __restrict__ xT,
                                                 const __hip_bfloat16* __restrict__ Wg,
                                                 const float* __restrict__ biasout,
                                                 float* __restrict__ out) {
  __shared__ __align__(64) char lds[2 * ABUF + LDS_B_SZ];
  const char* WgB = (const char*)Wg;
  const char* xTB = (const char*)xT;

  int blk = blockIdx.x;
  int nt = blk & 1;
  int pt = (blk >> 1) & 15;
  int b  = blk >> 5;
  int h0 = pt * 2;                 // output rows h0..h0+1 -> padded rows h0..h0+3

  int tid  = threadIdx.x;
  int lane = tid & 63;
  int wave = tid >> 6;            // 0..3
  int wm = wave & 1;              // n-half (64)
  int wk = wave >> 1;             // k-half
  int half = lane >> 5;           // 0..1
  int l31 = lane & 31;

  float16v acc[2][2];             // [m-subtile][p-subtile], 32x32 each
#pragma unroll
  for (int mt = 0; mt < 2; ++mt)
#pragma unroll
    for (int p2 = 0; p2 < 2; ++p2)
#pragma unroll
      for (int e = 0; e < 16; ++e) acc[mt][p2][e] = 0.f;

  // Step-invariant fragment offsets. k-octet g = wk*4 + ks*2 + half.
  int aoff[2][2], boff[2][2];
#pragma unroll
  for (int mt = 0; mt < 2; ++mt)
#pragma unroll
    for (int ks = 0; ks < 2; ++ks)
      aoff[mt][ks] = ((wk * 4 + ks * 2 + half) * 128 + wm * 64 + mt * 32 + l31) * 16;
#pragma unroll
  for (int p2 = 0; p2 < 2; ++p2)
#pragma unroll
    for (int ks = 0; ks < 2; ++ks)
      boff[p2][ks] = BBASE + ((wk * 4 + ks * 2 + half) * 136 + p2 * 34 + l31) * 16;

  auto stage_a = [&](int step, int buf) {
    int p = step / 9, s = step - p * 9;
    const char* g = WgB + (((s * 4 + p) * 2 + nt) * 16384);
#pragma unroll
    for (int i = 0; i < 4; ++i) {
      int slotbase = i * 256 + wave * 64;   // wave-uniform
      __builtin_amdgcn_global_load_lds(
          (const __attribute__((address_space(1))) void*)(g + (slotbase + lane) * 16),
          (__attribute__((address_space(3))) void*)(lds + buf * ABUF + slotbase * 16),
          16, 0, 0);
    }
  };

  auto stage_b = [&](int p) {
#pragma unroll
    for (int i = 0; i < 5; ++i) {
      int slot = i * 256 + tid;             // 1088 slots = [g][pos], pos = hh*34+ww
      if (slot < 1088) {
        int gq  = slot / 136;
        int pos = slot - gq * 136;
        int hh  = pos / 34;
        int ww  = pos - hh * 34;
        const char* g = xTB + (((b * 34 + h0 + hh) * 34 + ww) * 256 +
                               p * 64 + gq * 8) * 2;
        __builtin_amdgcn_global_load_lds(
            (const __attribute__((address_space(1))) void*)g,
            (__attribute__((address_space(3))) void*)(lds + BBASE +
                                                     (i * 256 + wave * 64) * 16),
            16, 0, 0);
      }
    }
  };

  auto do_step = [&](int step) {
    int p = step / 9, s = step - p * 9;
    int si = s / 3, sj = s - si * 3;
    int soff = (si * 34 + sj) * 16;           // wave-uniform
    int abase = (step & 1) * ABUF;
    short8 af[2][2], bf[2][2];
#pragma unroll
    for (int mt = 0; mt < 2; ++mt)
#pragma unroll
      for (int ks = 0; ks < 2; ++ks) af[mt][ks] = *(const short8*)(lds + abase + aoff[mt][ks]);
#pragma unroll
    for (int p2 = 0; p2 < 2; ++p2)
#pragma unroll
      for (int ks = 0; ks < 2; ++ks) bf[p2][ks] = *(const short8*)(lds + boff[p2][ks] + soff);
#pragma unroll
    for (int ks = 0; ks < 2; ++ks)
#pragma unroll
      for (int mt = 0; mt < 2; ++mt)
#pragma unroll
        for (int p2 = 0; p2 < 2; ++p2)
          acc[mt][p2] = __builtin_amdgcn_mfma_f32_32x32x16_bf16(af[mt][ks], bf[p2][ks],
                                                                acc[mt][p2], 0, 0, 0);
  };

  stage_a(0, 0);
  stage_b(0);
  __syncthreads();
  for (int step = 0; step < 36; ++step) {
    int p = step / 9, s = step - p * 9;
    if (s == 8) {
      if (p < 3) stage_a(step + 1, (step + 1) & 1);
      do_step(step);
      __syncthreads();
      if (p < 3) { stage_b(p + 1); __syncthreads(); }
    } else {
      stage_a(step + 1, (step + 1) & 1);
      do_step(step);
      __syncthreads();
    }
  }

  // Reduce k-halves via LDS (reuse A region; constant acc indices).
  // Round 1: wk1 -> wk0 on m-subtile 0. Round 2: wk0 -> wk1 on m-subtile 1.
  {
    __syncthreads();
    if (wk == 1) {
#pragma unroll
      for (int p2 = 0; p2 < 2; ++p2)
        *(float16v*)(lds + ((wm * 2 + p2) * 64 + lane) * 64) = acc[0][p2];
    }
    __syncthreads();
    if (wk == 0) {
#pragma unroll
      for (int p2 = 0; p2 < 2; ++p2)
        acc[0][p2] += *(const float16v*)(lds + ((wm * 2 + p2) * 64 + lane) * 64);
    }
    __syncthreads();
    if (wk == 0) {
#pragma unroll
      for (int p2 = 0; p2 < 2; ++p2)
        *(float16v*)(lds + ((wm * 2 + p2) * 64 + lane) * 64) = acc[1][p2];
    }
    __syncthreads();
    if (wk == 1) {
#pragma unroll
      for (int p2 = 0; p2 < 2; ++p2)
        acc[1][p2] += *(const float16v*)(lds + ((wm * 2 + p2) * 64 + lane) * 64);
    }
  }

  // Store: wk0 stores m-subtile 0, wk1 stores m-subtile 1. Constant indices.
  int wc = l31;
  if (wk == 0) {
    float bv[16];
#pragma unroll
    for (int reg = 0; reg < 16; ++reg) {
      int row = (reg & 3) + 8 * (reg >> 2) + 4 * half;
      bv[reg] = biasout[nt * 128 + wm * 64 + row];
    }
#pragma unroll
    for (int p2 = 0; p2 < 2; ++p2) {
      int hr = h0 + p2;
      float16v v = acc[0][p2];
#pragma unroll
      for (int reg = 0; reg < 16; ++reg) {
        int row = (reg & 3) + 8 * (reg >> 2) + 4 * half;
        int n = nt * 128 + wm * 64 + row;
        out[((b * 256 + n) * 32 + hr) * 32 + wc] = v[reg] + bv[reg];
      }
    }
  } else {
    float bv[16];
#pragma unroll
    for (int reg = 0; reg < 16; ++reg) {
      int row = (reg & 3) + 8 * (reg >> 2) + 4 * half;
      bv[reg] = biasout[nt * 128 + wm * 64 + 32 + row];
    }
#pragma unroll
    for (int p2 = 0; p2 < 2; ++p2) {
      int hr = h0 + p2;
      float16v v = acc[1][p2];
#pragma unroll
      for (int reg = 0; reg < 16; ++reg) {
        int row = (reg & 3) + 8 * (reg >> 2) + 4 * half;
        int n = nt * 128 + wm * 64 + 32 + row;
        out[((b * 256 + n) * 32 + hr) * 32 + wc] = v[reg] + bv[reg];
      }
    }
  }
}

// ---------------------------------------------------------------------------
extern "C" void kernel_launch(void* const* d_in, const int* in_sizes, int n_in,
                              void* d_out, int out_size, void* d_ws, size_t ws_size,
                              hipStream_t stream) {
  const float* x    = (const float*)d_in[0];
  const float* tw1  = (const float*)d_in[1];
  const float* tw2  = (const float*)d_in[2];
  const float* bias = (const float*)d_in[3];
  float* out = (float*)d_out;

  char* ws = (char*)d_ws;
  __hip_bfloat16* xT = (__hip_bfloat16*)ws;
  __hip_bfloat16* Wg = (__hip_bfloat16*)(ws + XT_BYTES);
  float* biasout     = (float*)(ws + XT_BYTES + WG_BYTES);

  k_transpose<<<512, 256, 0, stream>>>(x, xT);
  k_build_w<<<145, 256, 0, stream>>>(tw1, tw2, bias, Wg, biasout);
  k_gemm<<<512, 256, 0, stream>>>(xT, Wg, biasout, out);
}

// Round 9
// 118.980 us; speedup vs baseline: 1.0310x; 1.0310x over previous
//
#include <hip/hip_runtime.h>
#include <hip/hip_bf16.h>

typedef __attribute__((ext_vector_type(8))) short short8;
typedef __attribute__((ext_vector_type(16))) float float16v;

// Workspace layout (bytes):
//   xTg  bf16 [16 b][32 g][34 h][34 w][8 c]             : 9,469,952
//   Wg   bf16 [9 s][4 pair][4 nq][8 g][64 n][8 c]       : 1,179,648
//   biasout f32 [256]                                   : 1,024
#define XT_BYTES (16*32*34*34*8*2)
#define WG_BYTES (9*4*4*8*64*8*2)

// ---------------------------------------------------------------------------
// Kernel 0: x f32 [16][256][32][32] -> xTg bf16 [b][g][h][w][8c] (g = c-octet).
// 512 blocks = (b, h). float4 reads, LDS 256x33 transpose tile, short8 writes
// (32 consecutive w per 32-lane group -> contiguous 512 B segments).
// Blocks with h<2 zero the pad ring.
// ---------------------------------------------------------------------------
__global__ __launch_bounds__(256) void k_transpose(const float* __restrict__ x,
                                                   __hip_bfloat16* __restrict__ xTg) {
  __shared__ float tile[256 * 33];
  char* xTB = (char*)xTg;
  int blk = blockIdx.x;            // b*32 + h
  int h = blk & 31, b = blk >> 5;
  int tid = threadIdx.x;
  {
    int w4 = (tid & 7) * 4, c0 = tid >> 3;
#pragma unroll
    for (int j = 0; j < 8; ++j) {
      int ci = c0 + 32 * j;
      float4 v = *(const float4*)&x[((b * 256 + ci) * 32 + h) * 32 + w4];
      *(float4*)&tile[ci * 33 + w4] = v;
    }
  }
  __syncthreads();
  {
    int g0 = tid >> 5, w = tid & 31;
#pragma unroll
    for (int gi = 0; gi < 4; ++gi) {
      int g = gi * 8 + g0;
      union { short8 s; __hip_bfloat16 hv[8]; } pk;
#pragma unroll
      for (int cc = 0; cc < 8; ++cc)
        pk.hv[cc] = __float2bfloat16(tile[(g * 8 + cc) * 33 + w]);
      *(short8*)(xTB + ((((b * 32 + g) * 34 + h + 1) * 34) + (w + 1)) * 16) = pk.s;
    }
  }
  if (h < 2) {  // h==0 -> row 0 + col 0 ; h==1 -> row 33 + col 33 (all g)
    uint4 z4 = {0u, 0u, 0u, 0u};
    int edge = h * 33;
    for (int i = tid; i < 32 * 34; i += 256) {       // rows
      int g = i / 34, w = i - g * 34;
      *(uint4*)(xTB + ((((b * 32 + g) * 34 + edge) * 34) + w) * 16) = z4;
    }
    for (int i = tid; i < 32 * 32; i += 256) {       // cols (rows 1..32)
      int g = i >> 5, hh = 1 + (i & 31);
      *(uint4*)(xTB + ((((b * 32 + g) * 34 + hh) * 34) + edge) * 16) = z4;
    }
  }
}

// ---------------------------------------------------------------------------
// Kernel 1: build dense M_s = B2_s * B1_s, exact f32 in LDS. 145 blocks.
// Scatter order matches the gemm A slab: [s][pair][nq][g][n64][c8].
// ---------------------------------------------------------------------------
__global__ __launch_bounds__(256) void k_build_w(const float* __restrict__ tw1,
                                                 const float* __restrict__ tw2,
                                                 const float* __restrict__ bias,
                                                 __hip_bfloat16* __restrict__ Wg,
                                                 float* __restrict__ biasout) {
  __shared__ float mat[256 * 17];
  __shared__ __align__(16) float tws[2 * 255 * 4];
  int blk = blockIdx.x;
  int tid = threadIdx.x;
  if (blk == 144) {
    if (tid < 256) {
      float a = 0.f;
#pragma unroll
      for (int s = 0; s < 9; ++s) a += bias[s * 256 + tid];
      biasout[tid] = a * (1.f / 9.f);
    }
    return;
  }
  int sidx = blk >> 4;
  int colbase = (blk & 15) * 16;

  for (int i = tid; i < 255 * 4; i += 256) {
    tws[i]           = tw1[sidx * 255 * 4 + i];
    tws[255 * 4 + i] = tw2[sidx * 255 * 4 + i];
  }
  {
    int r = tid;
#pragma unroll
    for (int c = 0; c < 16; ++c) mat[r * 17 + c] = (r == colbase + c) ? 1.f : 0.f;
  }

  int c  = tid & 15;
  int pg = tid >> 4;
  for (int ph = 0; ph < 2; ++ph) {
    for (int si = 0; si < 8; ++si) {
      int lg = ph ? si : (7 - si);
      int st = 1 << lg;
      __syncthreads();
      float x0[8], x1[8], t0[8], t1[8], t2[8], t3[8];
#pragma unroll
      for (int i = 0; i < 8; ++i) {
        int qp = pg * 8 + i;
        int li = qp & (st - 1);
        int gi = qp >> lg;
        int p0 = (gi << (lg + 1)) | li;
        int p1 = p0 + st;
        float4 tv = *(const float4*)&tws[(ph * 255 + st - 1 + li) * 4];
        t0[i] = tv.x; t1[i] = tv.y; t2[i] = tv.z; t3[i] = tv.w;
        x0[i] = mat[p0 * 17 + c];
        x1[i] = mat[p1 * 17 + c];
      }
#pragma unroll
      for (int i = 0; i < 8; ++i) {
        int qp = pg * 8 + i;
        int li = qp & (st - 1);
        int gi = qp >> lg;
        int p0 = (gi << (lg + 1)) | li;
        int p1 = p0 + st;
        mat[p0 * 17 + c] = t0[i] * x0[i] + t1[i] * x1[i];
        mat[p1 * 17 + c] = t2[i] * x0[i] + t3[i] * x1[i];
      }
    }
  }
  __syncthreads();

  for (int idx = tid; idx < 256 * 16; idx += 256) {
    int r = idx >> 4, cc = idx & 15;
    int cg = colbase + cc;
    int pr = cg >> 6, g = (cg >> 3) & 7, c8 = cg & 7;
    int nq = r >> 6, nl = r & 63;
    int o = ((((sidx * 4 + pr) * 4 + nq) * 8 + g) * 64 + nl) * 8 + c8;
    Wg[o] = __float2bfloat16(mat[r * 17 + cc] * (1.f / 9.f));
  }
}

// ---------------------------------------------------------------------------
// Kernel 2 (R8: B direct-from-global, k-split x4): implicit-GEMM conv.
// Grid 1024 = 16 b x 16 ptile(2 rows = 64 pix) x 4 nq; 256 threads = 4 waves,
// wave = k-quarter wk. Wave tile 64n x 64pix (2x2 of 32x32 MFMA), K=16/step.
// A: 8 KB slab/step in LDS, double-buffered (16 KB total) -> 4 blocks/CU,
//    16 waves/CU, 4 waves/SIMD.
// B: direct coalesced global loads from xTg (w-contiguous 512 B per
//    half-wave), register double-buffered; per-block B set ~4.4 KB/chan-pair
//    re-read 9x -> L1-resident. No B barriers, no B LDS.
// k-quarters reduced via 3-round LDS tree; wave 0 stores with bias.
// ---------------------------------------------------------------------------
#define ABUF 8192

__global__ __launch_bounds__(256, 4) void k_gemm(const __hip_bfloat16* __restrict__ xTg,
                                                 const __hip_bfloat16* __restrict__ Wg,
                                                 const float* __restrict__ biasout,
                                                 float* __restrict__ out) {
  __shared__ __align__(64) char lds[2 * ABUF];
  const char* WgB = (const char*)Wg;
  const char* xTB = (const char*)xTg;

  int blk = blockIdx.x;
  int nq = blk & 3;
  int pt = (blk >> 2) & 15;
  int b  = blk >> 6;
  int h0 = pt * 2;                // output rows h0, h0+1

  int tid  = threadIdx.x;
  int lane = tid & 63;
  int wk   = tid >> 6;            // wave = k-quarter 0..3
  int half = lane >> 5;
  int l31  = lane & 31;

  float16v acc[2][2];             // [mt][p2]
#pragma unroll
  for (int mt = 0; mt < 2; ++mt)
#pragma unroll
    for (int p2 = 0; p2 < 2; ++p2)
#pragma unroll
      for (int e = 0; e < 16; ++e) acc[mt][p2][e] = 0.f;

  int aoff[2];
#pragma unroll
  for (int mt = 0; mt < 2; ++mt)
    aoff[mt] = ((2 * wk + half) * 64 + mt * 32 + l31) * 16;

  // B base in 16-byte units: octet (2wk+half) of chan-pair 0, row h0, col l31.
  int bbase = ((b * 32 + 2 * wk + half) * 34 + h0) * 34 + l31;

  auto stage_a = [&](int step, int buf) {
    int p = step / 9, s = step - p * 9;
    const char* g = WgB + ((s * 4 + p) * 4 + nq) * 8192;
#pragma unroll
    for (int i = 0; i < 2; ++i) {
      int slotbase = i * 256 + wk * 64;   // wave-uniform
      __builtin_amdgcn_global_load_lds(
          (const __attribute__((address_space(1))) void*)(g + (slotbase + lane) * 16),
          (__attribute__((address_space(3))) void*)(lds + buf * ABUF + slotbase * 16),
          16, 0, 0);
    }
  };

  auto load_b = [&](int step, short8* bf) {
    int p = step / 9, s = step - p * 9;
    int si = s / 3, sj = s - si * 3;
    int off = (bbase + p * (8 * 34 * 34) + si * 34 + sj) * 16;
    bf[0] = *(const short8*)(xTB + off);             // row h0+si   (p2=0)
    bf[1] = *(const short8*)(xTB + off + 34 * 16);   // row h0+1+si (p2=1)
  };

  short8 bcur[2], bnext[2];
  stage_a(0, 0);
  load_b(0, bcur);
  __syncthreads();

  for (int step = 0; step < 36; ++step) {
    if (step < 35) {
      stage_a(step + 1, (step + 1) & 1);
      load_b(step + 1, bnext);
    }
    int abase = (step & 1) * ABUF;
    short8 af0 = *(const short8*)(lds + abase + aoff[0]);
    short8 af1 = *(const short8*)(lds + abase + aoff[1]);
    acc[0][0] = __builtin_amdgcn_mfma_f32_32x32x16_bf16(af0, bcur[0], acc[0][0], 0, 0, 0);
    acc[0][1] = __builtin_amdgcn_mfma_f32_32x32x16_bf16(af0, bcur[1], acc[0][1], 0, 0, 0);
    acc[1][0] = __builtin_amdgcn_mfma_f32_32x32x16_bf16(af1, bcur[0], acc[1][0], 0, 0, 0);
    acc[1][1] = __builtin_amdgcn_mfma_f32_32x32x16_bf16(af1, bcur[1], acc[1][1], 0, 0, 0);
    __syncthreads();   // A dbuf handoff (vmcnt drain also completes bnext)
    bcur[0] = bnext[0];
    bcur[1] = bnext[1];
  }

  // Reduce k-quarters: (wk0+=wk2, wk1+=wk3) per mt, then wk0+=wk1. 16 KB buf.
  auto fptr = [&](int slot) { return (float16v*)(lds + slot * 4096 + lane * 64); };
  __syncthreads();
  if (wk >= 2) { *fptr((wk - 2) * 2 + 0) = acc[0][0]; *fptr((wk - 2) * 2 + 1) = acc[0][1]; }
  __syncthreads();
  if (wk < 2)  { acc[0][0] += *fptr(wk * 2 + 0); acc[0][1] += *fptr(wk * 2 + 1); }
  __syncthreads();
  if (wk >= 2) { *fptr((wk - 2) * 2 + 0) = acc[1][0]; *fptr((wk - 2) * 2 + 1) = acc[1][1]; }
  __syncthreads();
  if (wk < 2)  { acc[1][0] += *fptr(wk * 2 + 0); acc[1][1] += *fptr(wk * 2 + 1); }
  __syncthreads();
  if (wk == 1) { *fptr(0) = acc[0][0]; *fptr(1) = acc[0][1];
                 *fptr(2) = acc[1][0]; *fptr(3) = acc[1][1]; }
  __syncthreads();
  if (wk == 0) {
    acc[0][0] += *fptr(0); acc[0][1] += *fptr(1);
    acc[1][0] += *fptr(2); acc[1][1] += *fptr(3);
    // Store 64n x 64pix. D layout: col=l31, row=(reg&3)+8*(reg>>2)+4*half.
#pragma unroll
    for (int mt = 0; mt < 2; ++mt) {
#pragma unroll
      for (int reg = 0; reg < 16; ++reg) {
        int n = nq * 64 + mt * 32 + (reg & 3) + 8 * (reg >> 2) + 4 * half;
        float bv = biasout[n];
        out[((b * 256 + n) * 32 + h0) * 32 + l31]     = acc[mt][0][reg] + bv;
        out[((b * 256 + n) * 32 + h0 + 1) * 32 + l31] = acc[mt][1][reg] + bv;
      }
    }
  }
}

// ---------------------------------------------------------------------------
extern "C" void kernel_launch(void* const* d_in, const int* in_sizes, int n_in,
                              void* d_out, int out_size, void* d_ws, size_t ws_size,
                              hipStream_t stream) {
  const float* x    = (const float*)d_in[0];
  const float* tw1  = (const float*)d_in[1];
  const float* tw2  = (const float*)d_in[2];
  const float* bias = (const float*)d_in[3];
  float* out = (float*)d_out;

  char* ws = (char*)d_ws;
  __hip_bfloat16* xTg = (__hip_bfloat16*)ws;
  __hip_bfloat16* Wg  = (__hip_bfloat16*)(ws + XT_BYTES);
  float* biasout      = (float*)(ws + XT_BYTES + WG_BYTES);

  k_transpose<<<512, 256, 0, stream>>>(x, xTg);
  k_build_w<<<145, 256, 0, stream>>>(tw1, tw2, bias, Wg, biasout);
  k_gemm<<<1024, 256, 0, stream>>>(xTg, Wg, biasout, out);
}

// Round 10
// 111.869 us; speedup vs baseline: 1.0965x; 1.0636x over previous
//
#include <hip/hip_runtime.h>
#include <hip/hip_bf16.h>

typedef __attribute__((ext_vector_type(8))) short short8;
typedef __attribute__((ext_vector_type(16))) float float16v;

// Workspace layout (bytes):
//   xTg  bf16 [16 b][32 g][34 h][34 w][8 c]             : 9,469,952
//   Wg   bf16 [9 s][4 pair][4 nq][8 g][64 n][8 c]       : 1,179,648
//   biasout f32 [256]                                   : 1,024
#define XT_BYTES (16*32*34*34*8*2)
#define WG_BYTES (9*4*4*8*64*8*2)

// ---------------------------------------------------------------------------
// k_prep (R9: fused producer, saves one launch gap).
// Blocks 0..511: x f32 [16][256][32][32] -> xTg bf16 [b][g][h][w][8c]
//   (g = c-octet; pad ring zeroed by h<2 blocks).
// Blocks 512..655: dense M_s = B2_s*B1_s -> Wg in GEMM A order; 656: bias.
// ---------------------------------------------------------------------------
__global__ __launch_bounds__(256) void k_prep(const float* __restrict__ x,
                                              const float* __restrict__ tw1,
                                              const float* __restrict__ tw2,
                                              const float* __restrict__ bias,
                                              __hip_bfloat16* __restrict__ xTg,
                                              __hip_bfloat16* __restrict__ Wg,
                                              float* __restrict__ biasout) {
  __shared__ __align__(16) char smem[256 * 33 * 4];   // 33792 B, both phases fit
  int blk = blockIdx.x;
  int tid = threadIdx.x;

  if (blk < 512) {   // ---------------- transpose ----------------
    float* tile = (float*)smem;
    char* xTB = (char*)xTg;
    int h = blk & 31, b = blk >> 5;
    {
      int w4 = (tid & 7) * 4, c0 = tid >> 3;
#pragma unroll
      for (int j = 0; j < 8; ++j) {
        int ci = c0 + 32 * j;
        float4 v = *(const float4*)&x[((b * 256 + ci) * 32 + h) * 32 + w4];
        *(float4*)&tile[ci * 33 + w4] = v;
      }
    }
    __syncthreads();
    {
      int g0 = tid >> 5, w = tid & 31;
#pragma unroll
      for (int gi = 0; gi < 4; ++gi) {
        int g = gi * 8 + g0;
        union { short8 s; __hip_bfloat16 hv[8]; } pk;
#pragma unroll
        for (int cc = 0; cc < 8; ++cc)
          pk.hv[cc] = __float2bfloat16(tile[(g * 8 + cc) * 33 + w]);
        *(short8*)(xTB + ((((b * 32 + g) * 34 + h + 1) * 34) + (w + 1)) * 16) = pk.s;
      }
    }
    if (h < 2) {  // h==0 -> row 0 + col 0 ; h==1 -> row 33 + col 33 (all g)
      uint4 z4 = {0u, 0u, 0u, 0u};
      int edge = h * 33;
      for (int i = tid; i < 32 * 34; i += 256) {
        int g = i / 34, w = i - g * 34;
        *(uint4*)(xTB + ((((b * 32 + g) * 34 + edge) * 34) + w) * 16) = z4;
      }
      for (int i = tid; i < 32 * 32; i += 256) {
        int g = i >> 5, hh = 1 + (i & 31);
        *(uint4*)(xTB + ((((b * 32 + g) * 34 + hh) * 34) + edge) * 16) = z4;
      }
    }
    return;
  }

  // ---------------- build_w ----------------
  int wblk = blk - 512;
  if (wblk == 144) {
    if (tid < 256) {
      float a = 0.f;
#pragma unroll
      for (int s = 0; s < 9; ++s) a += bias[s * 256 + tid];
      biasout[tid] = a * (1.f / 9.f);
    }
    return;
  }
  float* mat = (float*)smem;              // 256*17*4 = 17408 B
  float* tws = (float*)(smem + 17408);    // 2*255*4*4 = 8160 B
  int sidx = wblk >> 4;
  int colbase = (wblk & 15) * 16;

  for (int i = tid; i < 255 * 4; i += 256) {
    tws[i]           = tw1[sidx * 255 * 4 + i];
    tws[255 * 4 + i] = tw2[sidx * 255 * 4 + i];
  }
  {
    int r = tid;
#pragma unroll
    for (int c = 0; c < 16; ++c) mat[r * 17 + c] = (r == colbase + c) ? 1.f : 0.f;
  }

  int c  = tid & 15;
  int pg = tid >> 4;
  for (int ph = 0; ph < 2; ++ph) {
    for (int si = 0; si < 8; ++si) {
      int lg = ph ? si : (7 - si);
      int st = 1 << lg;
      __syncthreads();
      float x0[8], x1[8], t0[8], t1[8], t2[8], t3[8];
#pragma unroll
      for (int i = 0; i < 8; ++i) {
        int qp = pg * 8 + i;
        int li = qp & (st - 1);
        int gi = qp >> lg;
        int p0 = (gi << (lg + 1)) | li;
        int p1 = p0 + st;
        float4 tv = *(const float4*)&tws[(ph * 255 + st - 1 + li) * 4];
        t0[i] = tv.x; t1[i] = tv.y; t2[i] = tv.z; t3[i] = tv.w;
        x0[i] = mat[p0 * 17 + c];
        x1[i] = mat[p1 * 17 + c];
      }
#pragma unroll
      for (int i = 0; i < 8; ++i) {
        int qp = pg * 8 + i;
        int li = qp & (st - 1);
        int gi = qp >> lg;
        int p0 = (gi << (lg + 1)) | li;
        int p1 = p0 + st;
        mat[p0 * 17 + c] = t0[i] * x0[i] + t1[i] * x1[i];
        mat[p1 * 17 + c] = t2[i] * x0[i] + t3[i] * x1[i];
      }
    }
  }
  __syncthreads();

  for (int idx = tid; idx < 256 * 16; idx += 256) {
    int r = idx >> 4, cc = idx & 15;
    int cg = colbase + cc;
    int pr = cg >> 6, g = (cg >> 3) & 7, c8 = cg & 7;
    int nq = r >> 6, nl = r & 63;
    int o = ((((sidx * 4 + pr) * 4 + nq) * 8 + g) * 64 + nl) * 8 + c8;
    Wg[o] = __float2bfloat16(mat[r * 17 + cc] * (1.f / 9.f));
  }
}

// ---------------------------------------------------------------------------
// k_gemm (R9: barrier-free K-loop). Grid 1024 = 16 b x 16 ptile(2 rows) x 4 nq;
// 256 threads = 4 waves = k-quarters. Wave tile 64n x 64pix (2x2 of 32x32).
// BOTH operands load straight from global into registers (A-frag and B-frag
// are each 512 B/half-wave coalesced reads; Wg slabs and the xTg halo are
// L2-resident). No LDS, no __syncthreads, no vmcnt(0) drains anywhere in the
// K-loop -- all waits are compiler register-dependency waitcnts, pipelined
// across the unrolled loop with 4 waves/SIMD (4 blocks/CU).
// LDS (16 KB) only for the epilogue k-quarter reduction.
// ---------------------------------------------------------------------------
__global__ __launch_bounds__(256, 4) void k_gemm(const __hip_bfloat16* __restrict__ xTg,
                                                 const __hip_bfloat16* __restrict__ Wg,
                                                 const float* __restrict__ biasout,
                                                 float* __restrict__ out) {
  __shared__ __align__(64) char lds[16384];
  const char* WgB = (const char*)Wg;
  const char* xTB = (const char*)xTg;

  int blk = blockIdx.x;
  int nq = blk & 3;
  int pt = (blk >> 2) & 15;
  int b  = blk >> 6;
  int h0 = pt * 2;                // output rows h0, h0+1

  int tid  = threadIdx.x;
  int lane = tid & 63;
  int wk   = tid >> 6;            // wave = k-quarter 0..3
  int half = lane >> 5;
  int l31  = lane & 31;

  float16v acc[2][2];             // [mt][p2]
#pragma unroll
  for (int mt = 0; mt < 2; ++mt)
#pragma unroll
    for (int p2 = 0; p2 < 2; ++p2)
#pragma unroll
      for (int e = 0; e < 16; ++e) acc[mt][p2][e] = 0.f;

  // A: within a slab, octet (2wk+half), row mt*32+l31 -> 16 B/lane contiguous.
  int aoff = ((2 * wk + half) * 64 + l31) * 16;
  // B: octet (2wk+half) of chan-pair p (global octet +8p), padded row h0, col l31.
  int bbase = ((((b * 32 + 2 * wk + half) * 34 + h0) * 34) + l31) * 16;

  for (int p = 0; p < 4; ++p) {
    const char* Bp = xTB + bbase + p * (8 * 34 * 34) * 16;
    const char* Ap = WgB + (p * 4 + nq) * 8192;
    for (int si = 0; si < 3; ++si) {
#pragma unroll
      for (int sj = 0; sj < 3; ++sj) {
        const char* Aslab = Ap + (si * 3 + sj) * (16 * 8192);
        short8 a0 = *(const short8*)(Aslab + aoff);
        short8 a1 = *(const short8*)(Aslab + aoff + 32 * 16);
        const char* Bq = Bp + (si * 34 + sj) * 16;
        short8 b0 = *(const short8*)(Bq);
        short8 b1 = *(const short8*)(Bq + 34 * 16);
        acc[0][0] = __builtin_amdgcn_mfma_f32_32x32x16_bf16(a0, b0, acc[0][0], 0, 0, 0);
        acc[0][1] = __builtin_amdgcn_mfma_f32_32x32x16_bf16(a0, b1, acc[0][1], 0, 0, 0);
        acc[1][0] = __builtin_amdgcn_mfma_f32_32x32x16_bf16(a1, b0, acc[1][0], 0, 0, 0);
        acc[1][1] = __builtin_amdgcn_mfma_f32_32x32x16_bf16(a1, b1, acc[1][1], 0, 0, 0);
      }
    }
  }

  // Reduce k-quarters: (wk0+=wk2, wk1+=wk3), then wk0+=wk1. Constant indices.
  auto fptr = [&](int slot) { return (float16v*)(lds + slot * 4096 + lane * 64); };
  __syncthreads();
  if (wk >= 2) { *fptr((wk - 2) * 2 + 0) = acc[0][0]; *fptr((wk - 2) * 2 + 1) = acc[0][1]; }
  __syncthreads();
  if (wk < 2)  { acc[0][0] += *fptr(wk * 2 + 0); acc[0][1] += *fptr(wk * 2 + 1); }
  __syncthreads();
  if (wk >= 2) { *fptr((wk - 2) * 2 + 0) = acc[1][0]; *fptr((wk - 2) * 2 + 1) = acc[1][1]; }
  __syncthreads();
  if (wk < 2)  { acc[1][0] += *fptr(wk * 2 + 0); acc[1][1] += *fptr(wk * 2 + 1); }
  __syncthreads();
  if (wk == 1) { *fptr(0) = acc[0][0]; *fptr(1) = acc[0][1];
                 *fptr(2) = acc[1][0]; *fptr(3) = acc[1][1]; }
  __syncthreads();
  if (wk == 0) {
    acc[0][0] += *fptr(0); acc[0][1] += *fptr(1);
    acc[1][0] += *fptr(2); acc[1][1] += *fptr(3);
    // Store 64n x 64pix. D layout: col=l31, row=(reg&3)+8*(reg>>2)+4*half.
#pragma unroll
    for (int mt = 0; mt < 2; ++mt) {
#pragma unroll
      for (int reg = 0; reg < 16; ++reg) {
        int n = nq * 64 + mt * 32 + (reg & 3) + 8 * (reg >> 2) + 4 * half;
        float bv = biasout[n];
        out[((b * 256 + n) * 32 + h0) * 32 + l31]     = acc[mt][0][reg] + bv;
        out[((b * 256 + n) * 32 + h0 + 1) * 32 + l31] = acc[mt][1][reg] + bv;
      }
    }
  }
}

// ---------------------------------------------------------------------------
extern "C" void kernel_launch(void* const* d_in, const int* in_sizes, int n_in,
                              void* d_out, int out_size, void* d_ws, size_t ws_size,
                              hipStream_t stream) {
  const float* x    = (const float*)d_in[0];
  const float* tw1  = (const float*)d_in[1];
  const float* tw2  = (const float*)d_in[2];
  const float* bias = (const float*)d_in[3];
  float* out = (float*)d_out;

  char* ws = (char*)d_ws;
  __hip_bfloat16* xTg = (__hip_bfloat16*)ws;
  __hip_bfloat16* Wg  = (__hip_bfloat16*)(ws + XT_BYTES);
  float* biasout      = (float*)(ws + XT_BYTES + WG_BYTES);

  k_prep<<<657, 256, 0, stream>>>(x, tw1, tw2, bias, xTg, Wg, biasout);
  k_gemm<<<1024, 256, 0, stream>>>(xTg, Wg, biasout, out);
}

// Round 11
// 109.828 us; speedup vs baseline: 1.1169x; 1.0186x over previous
//
#include <hip/hip_runtime.h>
#include <hip/hip_bf16.h>

typedef __attribute__((ext_vector_type(8))) short short8;
typedef __attribute__((ext_vector_type(4))) float float4v;
typedef __attribute__((ext_vector_type(16))) float float16v;

// Workspace layout (bytes):
//   xTg  bf16 [16 b][32 g][34 h][34 w][8 c]             : 9,469,952
//   Wg   bf16 [9 s][4 pair][4 nq][8 g][64 n][8 c]       : 1,179,648
//   biasout f32 [256]                                   : 1,024
#define XT_BYTES (16*32*34*34*8*2)
#define WG_BYTES (9*4*4*8*64*8*2)

// ---------------------------------------------------------------------------
// k_prep: fused producer.
// Blocks 0..511: x f32 [16][256][32][32] -> xTg bf16 [b][g][h][w][8c]
//   (g = c-octet; pad ring zeroed by h<2 blocks).
// Blocks 512..655: dense M_s = B2_s*B1_s -> Wg in GEMM A order; 656: bias.
// ---------------------------------------------------------------------------
__global__ __launch_bounds__(256) void k_prep(const float* __restrict__ x,
                                              const float* __restrict__ tw1,
                                              const float* __restrict__ tw2,
                                              const float* __restrict__ bias,
                                              __hip_bfloat16* __restrict__ xTg,
                                              __hip_bfloat16* __restrict__ Wg,
                                              float* __restrict__ biasout) {
  __shared__ __align__(16) char smem[256 * 33 * 4];   // 33792 B, both phases fit
  int blk = blockIdx.x;
  int tid = threadIdx.x;

  if (blk < 512) {   // ---------------- transpose ----------------
    float* tile = (float*)smem;
    char* xTB = (char*)xTg;
    int h = blk & 31, b = blk >> 5;
    {
      int w4 = (tid & 7) * 4, c0 = tid >> 3;
#pragma unroll
      for (int j = 0; j < 8; ++j) {
        int ci = c0 + 32 * j;
        float4 v = *(const float4*)&x[((b * 256 + ci) * 32 + h) * 32 + w4];
        *(float4*)&tile[ci * 33 + w4] = v;
      }
    }
    __syncthreads();
    {
      int g0 = tid >> 5, w = tid & 31;
#pragma unroll
      for (int gi = 0; gi < 4; ++gi) {
        int g = gi * 8 + g0;
        union { short8 s; __hip_bfloat16 hv[8]; } pk;
#pragma unroll
        for (int cc = 0; cc < 8; ++cc)
          pk.hv[cc] = __float2bfloat16(tile[(g * 8 + cc) * 33 + w]);
        *(short8*)(xTB + ((((b * 32 + g) * 34 + h + 1) * 34) + (w + 1)) * 16) = pk.s;
      }
    }
    if (h < 2) {  // h==0 -> row 0 + col 0 ; h==1 -> row 33 + col 33 (all g)
      uint4 z4 = {0u, 0u, 0u, 0u};
      int edge = h * 33;
      for (int i = tid; i < 32 * 34; i += 256) {
        int g = i / 34, w = i - g * 34;
        *(uint4*)(xTB + ((((b * 32 + g) * 34 + edge) * 34) + w) * 16) = z4;
      }
      for (int i = tid; i < 32 * 32; i += 256) {
        int g = i >> 5, hh = 1 + (i & 31);
        *(uint4*)(xTB + ((((b * 32 + g) * 34 + hh) * 34) + edge) * 16) = z4;
      }
    }
    return;
  }

  // ---------------- build_w ----------------
  int wblk = blk - 512;
  if (wblk == 144) {
    if (tid < 256) {
      float a = 0.f;
#pragma unroll
      for (int s = 0; s < 9; ++s) a += bias[s * 256 + tid];
      biasout[tid] = a * (1.f / 9.f);
    }
    return;
  }
  float* mat = (float*)smem;              // 256*17*4 = 17408 B
  float* tws = (float*)(smem + 17408);    // 2*255*4*4 = 8160 B
  int sidx = wblk >> 4;
  int colbase = (wblk & 15) * 16;

  for (int i = tid; i < 255 * 4; i += 256) {
    tws[i]           = tw1[sidx * 255 * 4 + i];
    tws[255 * 4 + i] = tw2[sidx * 255 * 4 + i];
  }
  {
    int r = tid;
#pragma unroll
    for (int c = 0; c < 16; ++c) mat[r * 17 + c] = (r == colbase + c) ? 1.f : 0.f;
  }

  int c  = tid & 15;
  int pg = tid >> 4;
  for (int ph = 0; ph < 2; ++ph) {
    for (int si = 0; si < 8; ++si) {
      int lg = ph ? si : (7 - si);
      int st = 1 << lg;
      __syncthreads();
      float x0[8], x1[8], t0[8], t1[8], t2[8], t3[8];
#pragma unroll
      for (int i = 0; i < 8; ++i) {
        int qp = pg * 8 + i;
        int li = qp & (st - 1);
        int gi = qp >> lg;
        int p0 = (gi << (lg + 1)) | li;
        int p1 = p0 + st;
        float4 tv = *(const float4*)&tws[(ph * 255 + st - 1 + li) * 4];
        t0[i] = tv.x; t1[i] = tv.y; t2[i] = tv.z; t3[i] = tv.w;
        x0[i] = mat[p0 * 17 + c];
        x1[i] = mat[p1 * 17 + c];
      }
#pragma unroll
      for (int i = 0; i < 8; ++i) {
        int qp = pg * 8 + i;
        int li = qp & (st - 1);
        int gi = qp >> lg;
        int p0 = (gi << (lg + 1)) | li;
        int p1 = p0 + st;
        mat[p0 * 17 + c] = t0[i] * x0[i] + t1[i] * x1[i];
        mat[p1 * 17 + c] = t2[i] * x0[i] + t3[i] * x1[i];
      }
    }
  }
  __syncthreads();

  for (int idx = tid; idx < 256 * 16; idx += 256) {
    int r = idx >> 4, cc = idx & 15;
    int cg = colbase + cc;
    int pr = cg >> 6, g = (cg >> 3) & 7, c8 = cg & 7;
    int nq = r >> 6, nl = r & 63;
    int o = ((((sidx * 4 + pr) * 4 + nq) * 8 + g) * 64 + nl) * 8 + c8;
    Wg[o] = __float2bfloat16(mat[r * 17 + cc] * (1.f / 9.f));
  }
}

// ---------------------------------------------------------------------------
// k_gemm (R10: conflict-free epilogue + wider pipeline window).
// Grid 1024 = 16 b x 16 ptile(2 rows) x 4 nq; 256 threads = 4 waves =
// k-quarters. Wave tile 64n x 64pix (2x2 of 32x32). Barrier-free K-loop,
// both operands straight from global (coalesced 512 B/half-wave, L1/L2-hit).
// p-loop unroll 2 -> 18-iter scheduling window. Epilogue k-reduction uses
// lane*16-stride float4 chunks (R9's lane*64 stride cost 1.77e6 bank-conflict
// cycles = ~2.9 us/CU).
// ---------------------------------------------------------------------------
__global__ __launch_bounds__(256, 4) void k_gemm(const __hip_bfloat16* __restrict__ xTg,
                                                 const __hip_bfloat16* __restrict__ Wg,
                                                 const float* __restrict__ biasout,
                                                 float* __restrict__ out) {
  __shared__ __align__(64) char lds[16384];
  const char* WgB = (const char*)Wg;
  const char* xTB = (const char*)xTg;

  int blk = blockIdx.x;
  int nq = blk & 3;
  int pt = (blk >> 2) & 15;
  int b  = blk >> 6;
  int h0 = pt * 2;                // output rows h0, h0+1

  int tid  = threadIdx.x;
  int lane = tid & 63;
  int wk   = tid >> 6;            // wave = k-quarter 0..3
  int half = lane >> 5;
  int l31  = lane & 31;

  float16v acc[2][2];             // [mt][p2]
#pragma unroll
  for (int mt = 0; mt < 2; ++mt)
#pragma unroll
    for (int p2 = 0; p2 < 2; ++p2)
#pragma unroll
      for (int e = 0; e < 16; ++e) acc[mt][p2][e] = 0.f;

  // A: within a slab, octet (2wk+half), row mt*32+l31 -> 16 B/lane contiguous.
  int aoff = ((2 * wk + half) * 64 + l31) * 16;
  // B: octet (2wk+half) of chan-pair p (global octet +8p), padded row h0, col l31.
  int bbase = ((((b * 32 + 2 * wk + half) * 34 + h0) * 34) + l31) * 16;

#pragma unroll 2
  for (int p = 0; p < 4; ++p) {
    const char* Bp = xTB + bbase + p * (8 * 34 * 34) * 16;
    const char* Ap = WgB + (p * 4 + nq) * 8192;
#pragma unroll
    for (int si = 0; si < 3; ++si) {
#pragma unroll
      for (int sj = 0; sj < 3; ++sj) {
        const char* Aslab = Ap + (si * 3 + sj) * (16 * 8192);
        short8 a0 = *(const short8*)(Aslab + aoff);
        short8 a1 = *(const short8*)(Aslab + aoff + 32 * 16);
        const char* Bq = Bp + (si * 34 + sj) * 16;
        short8 b0 = *(const short8*)(Bq);
        short8 b1 = *(const short8*)(Bq + 34 * 16);
        acc[0][0] = __builtin_amdgcn_mfma_f32_32x32x16_bf16(a0, b0, acc[0][0], 0, 0, 0);
        acc[0][1] = __builtin_amdgcn_mfma_f32_32x32x16_bf16(a0, b1, acc[0][1], 0, 0, 0);
        acc[1][0] = __builtin_amdgcn_mfma_f32_32x32x16_bf16(a1, b0, acc[1][0], 0, 0, 0);
        acc[1][1] = __builtin_amdgcn_mfma_f32_32x32x16_bf16(a1, b1, acc[1][1], 0, 0, 0);
      }
    }
  }

  // k-quarter reduction. Conflict-free layout: slot*4096 + q*1024 + lane*16
  // (lane stride 16 B -> even 32-bank spread, bandwidth-floor phases).
  auto st16 = [&](int slot, const float16v& v) {
    char* base = lds + slot * 4096 + lane * 16;
    *(float4v*)(base)        = (float4v){v[0],  v[1],  v[2],  v[3]};
    *(float4v*)(base + 1024) = (float4v){v[4],  v[5],  v[6],  v[7]};
    *(float4v*)(base + 2048) = (float4v){v[8],  v[9],  v[10], v[11]};
    *(float4v*)(base + 3072) = (float4v){v[12], v[13], v[14], v[15]};
  };
  auto ld16add = [&](int slot, float16v& v) {
    const char* base = lds + slot * 4096 + lane * 16;
    float4v t0 = *(const float4v*)(base);
    float4v t1 = *(const float4v*)(base + 1024);
    float4v t2 = *(const float4v*)(base + 2048);
    float4v t3 = *(const float4v*)(base + 3072);
    v[0] += t0[0]; v[1] += t0[1]; v[2]  += t0[2]; v[3]  += t0[3];
    v[4] += t1[0]; v[5] += t1[1]; v[6]  += t1[2]; v[7]  += t1[3];
    v[8] += t2[0]; v[9] += t2[1]; v[10] += t2[2]; v[11] += t2[3];
    v[12] += t3[0]; v[13] += t3[1]; v[14] += t3[2]; v[15] += t3[3];
  };

  __syncthreads();
  if (wk >= 2) { st16((wk - 2) * 2 + 0, acc[0][0]); st16((wk - 2) * 2 + 1, acc[0][1]); }
  __syncthreads();
  if (wk < 2)  { ld16add(wk * 2 + 0, acc[0][0]); ld16add(wk * 2 + 1, acc[0][1]); }
  __syncthreads();
  if (wk >= 2) { st16((wk - 2) * 2 + 0, acc[1][0]); st16((wk - 2) * 2 + 1, acc[1][1]); }
  __syncthreads();
  if (wk < 2)  { ld16add(wk * 2 + 0, acc[1][0]); ld16add(wk * 2 + 1, acc[1][1]); }
  __syncthreads();
  if (wk == 1) { st16(0, acc[0][0]); st16(1, acc[0][1]);
                 st16(2, acc[1][0]); st16(3, acc[1][1]); }
  __syncthreads();
  if (wk == 0) {
    ld16add(0, acc[0][0]); ld16add(1, acc[0][1]);
    ld16add(2, acc[1][0]); ld16add(3, acc[1][1]);
    // Store 64n x 64pix. D layout: col=l31, row=(reg&3)+8*(reg>>2)+4*half.
#pragma unroll
    for (int mt = 0; mt < 2; ++mt) {
#pragma unroll
      for (int reg = 0; reg < 16; ++reg) {
        int n = nq * 64 + mt * 32 + (reg & 3) + 8 * (reg >> 2) + 4 * half;
        float bv = biasout[n];
        out[((b * 256 + n) * 32 + h0) * 32 + l31]     = acc[mt][0][reg] + bv;
        out[((b * 256 + n) * 32 + h0 + 1) * 32 + l31] = acc[mt][1][reg] + bv;
      }
    }
  }
}

// ---------------------------------------------------------------------------
extern "C" void kernel_launch(void* const* d_in, const int* in_sizes, int n_in,
                              void* d_out, int out_size, void* d_ws, size_t ws_size,
                              hipStream_t stream) {
  const float* x    = (const float*)d_in[0];
  const float* tw1  = (const float*)d_in[1];
  const float* tw2  = (const float*)d_in[2];
  const float* bias = (const float*)d_in[3];
  float* out = (float*)d_out;

  char* ws = (char*)d_ws;
  __hip_bfloat16* xTg = (__hip_bfloat16*)ws;
  __hip_bfloat16* Wg  = (__hip_bfloat16*)(ws + XT_BYTES);
  float* biasout      = (float*)(ws + XT_BYTES + WG_BYTES);

  k_prep<<<657, 256, 0, stream>>>(x, tw1, tw2, bias, xTg, Wg, biasout);
  k_gemm<<<1024, 256, 0, stream>>>(xTg, Wg, biasout, out);
}

// Round 13
// 109.201 us; speedup vs baseline: 1.1233x; 1.0057x over previous
//
#include <hip/hip_runtime.h>
#include <hip/hip_bf16.h>

typedef __attribute__((ext_vector_type(8))) short short8;
typedef __attribute__((ext_vector_type(4))) float float4v;
typedef __attribute__((ext_vector_type(16))) float float16v;

// Workspace layout (bytes):
//   xTg  bf16 [16 b][32 g][34 h][34 w][8 c]             : 9,469,952
//   Wg   bf16 [9 s][4 pair][4 nq][8 g][64 n][8 c]       : 1,179,648
//   biasout f32 [256]                                   : 1,024
#define XT_BYTES (16*32*34*34*8*2)
#define WG_BYTES (9*4*4*8*64*8*2)

// ---------------------------------------------------------------------------
// k_prep: fused producer.
// Blocks 0..511: x f32 [16][256][32][32] -> xTg bf16 [b][g][h][w][8c]
//   (g = c-octet; pad ring zeroed by h<2 blocks).
// Blocks 512..655: dense M_s = B2_s*B1_s -> Wg in GEMM A order; 656: bias.
// ---------------------------------------------------------------------------
__global__ __launch_bounds__(256) void k_prep(const float* __restrict__ x,
                                              const float* __restrict__ tw1,
                                              const float* __restrict__ tw2,
                                              const float* __restrict__ bias,
                                              __hip_bfloat16* __restrict__ xTg,
                                              __hip_bfloat16* __restrict__ Wg,
                                              float* __restrict__ biasout) {
  __shared__ __align__(16) char smem[256 * 33 * 4];   // 33792 B, both phases fit
  int blk = blockIdx.x;
  int tid = threadIdx.x;

  if (blk < 512) {   // ---------------- transpose ----------------
    float* tile = (float*)smem;
    char* xTB = (char*)xTg;
    int h = blk & 31, b = blk >> 5;
    {
      int w4 = (tid & 7) * 4, c0 = tid >> 3;
#pragma unroll
      for (int j = 0; j < 8; ++j) {
        int ci = c0 + 32 * j;
        float4 v = *(const float4*)&x[((b * 256 + ci) * 32 + h) * 32 + w4];
        *(float4*)&tile[ci * 33 + w4] = v;
      }
    }
    __syncthreads();
    {
      int g0 = tid >> 5, w = tid & 31;
#pragma unroll
      for (int gi = 0; gi < 4; ++gi) {
        int g = gi * 8 + g0;
        union { short8 s; __hip_bfloat16 hv[8]; } pk;
#pragma unroll
        for (int cc = 0; cc < 8; ++cc)
          pk.hv[cc] = __float2bfloat16(tile[(g * 8 + cc) * 33 + w]);
        *(short8*)(xTB + ((((b * 32 + g) * 34 + h + 1) * 34) + (w + 1)) * 16) = pk.s;
      }
    }
    if (h < 2) {  // h==0 -> row 0 + col 0 ; h==1 -> row 33 + col 33 (all g)
      uint4 z4 = {0u, 0u, 0u, 0u};
      int edge = h * 33;
      for (int i = tid; i < 32 * 34; i += 256) {
        int g = i / 34, w = i - g * 34;
        *(uint4*)(xTB + ((((b * 32 + g) * 34 + edge) * 34) + w) * 16) = z4;
      }
      for (int i = tid; i < 32 * 32; i += 256) {
        int g = i >> 5, hh = 1 + (i & 31);
        *(uint4*)(xTB + ((((b * 32 + g) * 34 + hh) * 34) + edge) * 16) = z4;
      }
    }
    return;
  }

  // ---------------- build_w ----------------
  int wblk = blk - 512;
  if (wblk == 144) {
    if (tid < 256) {
      float a = 0.f;
#pragma unroll
      for (int s = 0; s < 9; ++s) a += bias[s * 256 + tid];
      biasout[tid] = a * (1.f / 9.f);
    }
    return;
  }
  float* mat = (float*)smem;              // 256*17*4 = 17408 B
  float* tws = (float*)(smem + 17408);    // 2*255*4*4 = 8160 B
  int sidx = wblk >> 4;
  int colbase = (wblk & 15) * 16;

  for (int i = tid; i < 255 * 4; i += 256) {
    tws[i]           = tw1[sidx * 255 * 4 + i];
    tws[255 * 4 + i] = tw2[sidx * 255 * 4 + i];
  }
  {
    int r = tid;
#pragma unroll
    for (int c = 0; c < 16; ++c) mat[r * 17 + c] = (r == colbase + c) ? 1.f : 0.f;
  }

  int c  = tid & 15;
  int pg = tid >> 4;
  for (int ph = 0; ph < 2; ++ph) {
    for (int si = 0; si < 8; ++si) {
      int lg = ph ? si : (7 - si);
      int st = 1 << lg;
      __syncthreads();
      float x0[8], x1[8], t0[8], t1[8], t2[8], t3[8];
#pragma unroll
      for (int i = 0; i < 8; ++i) {
        int qp = pg * 8 + i;
        int li = qp & (st - 1);
        int gi = qp >> lg;
        int p0 = (gi << (lg + 1)) | li;
        int p1 = p0 + st;
        float4 tv = *(const float4*)&tws[(ph * 255 + st - 1 + li) * 4];
        t0[i] = tv.x; t1[i] = tv.y; t2[i] = tv.z; t3[i] = tv.w;
        x0[i] = mat[p0 * 17 + c];
        x1[i] = mat[p1 * 17 + c];
      }
#pragma unroll
      for (int i = 0; i < 8; ++i) {
        int qp = pg * 8 + i;
        int li = qp & (st - 1);
        int gi = qp >> lg;
        int p0 = (gi << (lg + 1)) | li;
        int p1 = p0 + st;
        mat[p0 * 17 + c] = t0[i] * x0[i] + t1[i] * x1[i];
        mat[p1 * 17 + c] = t2[i] * x0[i] + t3[i] * x1[i];
      }
    }
  }
  __syncthreads();

  for (int idx = tid; idx < 256 * 16; idx += 256) {
    int r = idx >> 4, cc = idx & 15;
    int cg = colbase + cc;
    int pr = cg >> 6, g = (cg >> 3) & 7, c8 = cg & 7;
    int nq = r >> 6, nl = r & 63;
    int o = ((((sidx * 4 + pr) * 4 + nq) * 8 + g) * 64 + nl) * 8 + c8;
    Wg[o] = __float2bfloat16(mat[r * 17 + cc] * (1.f / 9.f));
  }
}

// ---------------------------------------------------------------------------
// k_gemm (R12 = R11 resubmit after broker timeout): 4-row ptile, halved A L2
// traffic. Grid 512 = 16 b x 8 ptile(4 rows = 128 pix) x 4 nq; 256 threads =
// 4 waves = k-quarters. Wave tile 64n x 128pix (2x4 of 32x32), acc[2][4].
// Barrier-free K-loop, both operands direct from global (coalesced
// 512 B/half-wave). A-slab L2 traffic: 512 blocks x 288 KB = 147 MB (half of
// R10's 295 MB -- R10's gemm was L2-BW-bound on A). launch_bounds(256,2) ->
// 2 blocks/CU; latency hiding via the 18-step unrolled window (no K barriers).
// Epilogue k-reduction: conflict-free lane*16 chunks, 8 x 4 KB slots.
// ---------------------------------------------------------------------------
__global__ __launch_bounds__(256, 2) void k_gemm(const __hip_bfloat16* __restrict__ xTg,
                                                 const __hip_bfloat16* __restrict__ Wg,
                                                 const float* __restrict__ biasout,
                                                 float* __restrict__ out) {
  __shared__ __align__(64) char lds[32768];
  const char* WgB = (const char*)Wg;
  const char* xTB = (const char*)xTg;

  int blk = blockIdx.x;
  int nq = blk & 3;
  int pt = (blk >> 2) & 7;
  int b  = blk >> 5;
  int h0 = pt * 4;                // output rows h0..h0+3

  int tid  = threadIdx.x;
  int lane = tid & 63;
  int wk   = tid >> 6;            // wave = k-quarter 0..3
  int half = lane >> 5;
  int l31  = lane & 31;

  float16v acc[2][4];             // [mt][p2]
#pragma unroll
  for (int mt = 0; mt < 2; ++mt)
#pragma unroll
    for (int p2 = 0; p2 < 4; ++p2)
#pragma unroll
      for (int e = 0; e < 16; ++e) acc[mt][p2][e] = 0.f;

  // A: within a slab, octet (2wk+half), row mt*32+l31 -> 16 B/lane contiguous.
  int aoff = ((2 * wk + half) * 64 + l31) * 16;
  // B: octet (2wk+half) of chan-pair p (global octet +8p), padded row h0, col l31.
  int bbase = ((((b * 32 + 2 * wk + half) * 34 + h0) * 34) + l31) * 16;

#pragma unroll 2
  for (int p = 0; p < 4; ++p) {
    const char* Bp = xTB + bbase + p * (8 * 34 * 34) * 16;
    const char* Ap = WgB + (p * 4 + nq) * 8192;
#pragma unroll
    for (int si = 0; si < 3; ++si) {
#pragma unroll
      for (int sj = 0; sj < 3; ++sj) {
        const char* Aslab = Ap + (si * 3 + sj) * (16 * 8192);
        short8 a0 = *(const short8*)(Aslab + aoff);
        short8 a1 = *(const short8*)(Aslab + aoff + 32 * 16);
        const char* Bq = Bp + (si * 34 + sj) * 16;
        short8 b0 = *(const short8*)(Bq);
        short8 b1 = *(const short8*)(Bq + 34 * 16);
        short8 b2 = *(const short8*)(Bq + 68 * 16);
        short8 b3 = *(const short8*)(Bq + 102 * 16);
        acc[0][0] = __builtin_amdgcn_mfma_f32_32x32x16_bf16(a0, b0, acc[0][0], 0, 0, 0);
        acc[0][1] = __builtin_amdgcn_mfma_f32_32x32x16_bf16(a0, b1, acc[0][1], 0, 0, 0);
        acc[0][2] = __builtin_amdgcn_mfma_f32_32x32x16_bf16(a0, b2, acc[0][2], 0, 0, 0);
        acc[0][3] = __builtin_amdgcn_mfma_f32_32x32x16_bf16(a0, b3, acc[0][3], 0, 0, 0);
        acc[1][0] = __builtin_amdgcn_mfma_f32_32x32x16_bf16(a1, b0, acc[1][0], 0, 0, 0);
        acc[1][1] = __builtin_amdgcn_mfma_f32_32x32x16_bf16(a1, b1, acc[1][1], 0, 0, 0);
        acc[1][2] = __builtin_amdgcn_mfma_f32_32x32x16_bf16(a1, b2, acc[1][2], 0, 0, 0);
        acc[1][3] = __builtin_amdgcn_mfma_f32_32x32x16_bf16(a1, b3, acc[1][3], 0, 0, 0);
      }
    }
  }

  // k-quarter reduction. Conflict-free: slot*4096 + lane*16, 4 chunks @ +1024.
  auto st16 = [&](int slot, const float16v& v) {
    char* base = lds + slot * 4096 + lane * 16;
    *(float4v*)(base)        = (float4v){v[0],  v[1],  v[2],  v[3]};
    *(float4v*)(base + 1024) = (float4v){v[4],  v[5],  v[6],  v[7]};
    *(float4v*)(base + 2048) = (float4v){v[8],  v[9],  v[10], v[11]};
    *(float4v*)(base + 3072) = (float4v){v[12], v[13], v[14], v[15]};
  };
  auto ld16add = [&](int slot, float16v& v) {
    const char* base = lds + slot * 4096 + lane * 16;
    float4v t0 = *(const float4v*)(base);
    float4v t1 = *(const float4v*)(base + 1024);
    float4v t2 = *(const float4v*)(base + 2048);
    float4v t3 = *(const float4v*)(base + 3072);
    v[0] += t0[0]; v[1] += t0[1]; v[2]  += t0[2]; v[3]  += t0[3];
    v[4] += t1[0]; v[5] += t1[1]; v[6]  += t1[2]; v[7]  += t1[3];
    v[8] += t2[0]; v[9] += t2[1]; v[10] += t2[2]; v[11] += t2[3];
    v[12] += t3[0]; v[13] += t3[1]; v[14] += t3[2]; v[15] += t3[3];
  };

  __syncthreads();
  if (wk >= 2) {
#pragma unroll
    for (int p2 = 0; p2 < 4; ++p2) st16((wk - 2) * 4 + p2, acc[0][p2]);
  }
  __syncthreads();
  if (wk < 2) {
#pragma unroll
    for (int p2 = 0; p2 < 4; ++p2) ld16add(wk * 4 + p2, acc[0][p2]);
  }
  __syncthreads();
  if (wk >= 2) {
#pragma unroll
    for (int p2 = 0; p2 < 4; ++p2) st16((wk - 2) * 4 + p2, acc[1][p2]);
  }
  __syncthreads();
  if (wk < 2) {
#pragma unroll
    for (int p2 = 0; p2 < 4; ++p2) ld16add(wk * 4 + p2, acc[1][p2]);
  }
  __syncthreads();
  if (wk == 1) {
#pragma unroll
    for (int p2 = 0; p2 < 4; ++p2) { st16(p2, acc[0][p2]); st16(4 + p2, acc[1][p2]); }
  }
  __syncthreads();
  if (wk == 0) {
#pragma unroll
    for (int p2 = 0; p2 < 4; ++p2) { ld16add(p2, acc[0][p2]); ld16add(4 + p2, acc[1][p2]); }
    // Store 64n x 128pix. D layout: col=l31, row=(reg&3)+8*(reg>>2)+4*half.
#pragma unroll
    for (int mt = 0; mt < 2; ++mt) {
#pragma unroll
      for (int reg = 0; reg < 16; ++reg) {
        int n = nq * 64 + mt * 32 + (reg & 3) + 8 * (reg >> 2) + 4 * half;
        float bv = biasout[n];
#pragma unroll
        for (int p2 = 0; p2 < 4; ++p2)
          out[((b * 256 + n) * 32 + h0 + p2) * 32 + l31] = acc[mt][p2][reg] + bv;
      }
    }
  }
}

// ---------------------------------------------------------------------------
extern "C" void kernel_launch(void* const* d_in, const int* in_sizes, int n_in,
                              void* d_out, int out_size, void* d_ws, size_t ws_size,
                              hipStream_t stream) {
  const float* x    = (const float*)d_in[0];
  const float* tw1  = (const float*)d_in[1];
  const float* tw2  = (const float*)d_in[2];
  const float* bias = (const float*)d_in[3];
  float* out = (float*)d_out;

  char* ws = (char*)d_ws;
  __hip_bfloat16* xTg = (__hip_bfloat16*)ws;
  __hip_bfloat16* Wg  = (__hip_bfloat16*)(ws + XT_BYTES);
  float* biasout      = (float*)(ws + XT_BYTES + WG_BYTES);

  k_prep<<<657, 256, 0, stream>>>(x, tw1, tw2, bias, xTg, Wg, biasout);
  k_gemm<<<512, 256, 0, stream>>>(xTg, Wg, biasout, out);
}